// Round 1
// baseline (2489.264 us; speedup 1.0000x reference)
//
#include <hip/hip_runtime.h>

typedef unsigned long long u64;
typedef unsigned int u32;

#define NB 8
#define ND 64
#define NPIX 65536   // 256*256

// monotone float->uint encoding (order-preserving for all reals)
__device__ __forceinline__ u32 fsort(float f){
  u32 u = __float_as_uint(f);
  return (u & 0x80000000u) ? ~u : (u | 0x80000000u);
}
__device__ __forceinline__ float funsort(u32 s){
  u32 u = (s & 0x80000000u) ? (s ^ 0x80000000u) : ~s;
  return __uint_as_float(u);
}

// ---------------- init: zero packed best-map, init use map + pos sentinels ----
__global__ void init_kernel(u64* __restrict__ packed, float* __restrict__ u,
                            int* __restrict__ pxy){
  int idx = blockIdx.x * 256 + threadIdx.x;
  if (idx < NB * NPIX){
    packed[idx] = 0ull;
    int p = idx & (NPIX - 1);
    int x = p >> 8, y = p & 255;
    u[idx] = (x >= 16 && x < 240 && y >= 16 && y < 240) ? 1.0f : 0.0f;
  }
  if (idx < 2 * NB) pxy[idx] = -100000;  // sentinel: first iter tmap==1 everywhere
}

// ---------------- conv + per-pixel max over d (fused) -----------------------
// conv[b,d,x,y] = sum_{fy,fx} input[b,(x+fy-16)%256,(y+fx-16)%256] * filt[d,fy,fx]
// block: 64x64 output tile for one b, 16 d's; atomicMax-combine packed (val,d)
__global__ __launch_bounds__(256) void conv_best_kernel(
    const float* __restrict__ input, const float* __restrict__ filt,
    const float* __restrict__ prior, u64* __restrict__ packed)
{
  __shared__ float sin_[96 * 96];
  __shared__ float sflt[33 * 36];
  const int tile = blockIdx.x;        // 0..15
  const int b    = blockIdx.y;        // 0..7
  const int g    = blockIdx.z;        // 0..3 (16 d's each)
  const int tX = (tile >> 2) << 6;
  const int tY = (tile & 3) << 6;
  const int tid = threadIdx.x;

  const float* inb = input + b * NPIX;
  for (int k = tid; k < 96 * 96; k += 256){
    int iy = k / 96, ix = k - iy * 96;
    int gx = (tX + iy - 16) & 255;
    int gy = (tY + ix - 16) & 255;
    sin_[k] = inb[(gx << 8) + gy];
  }

  const int ty = tid >> 4, tx = tid & 15;
  const int oy = ty << 2, ox = tx << 2;

  float bv[16];
  int   bd[16];
  #pragma unroll
  for (int i = 0; i < 16; ++i){ bv[i] = -3e38f; bd[i] = 0; }

  for (int dl = 0; dl < 16; ++dl){
    const int d = (g << 4) + dl;
    __syncthreads();   // covers input staging (first iter) + sflt reuse
    for (int k = tid; k < 33 * 33; k += 256){
      int fy = k / 33;
      sflt[fy * 36 + (k - fy * 33)] = filt[d * 1089 + k];
    }
    __syncthreads();

    float acc[4][4];
    #pragma unroll
    for (int r = 0; r < 4; ++r)
      #pragma unroll
      for (int c = 0; c < 4; ++c) acc[r][c] = 0.f;

    #pragma unroll 1
    for (int fy = 0; fy < 33; ++fy){
      float fr[36];
      {
        const float4* fp = (const float4*)(sflt + fy * 36);
        #pragma unroll
        for (int q = 0; q < 9; ++q){
          float4 t = fp[q];
          fr[4*q+0] = t.x; fr[4*q+1] = t.y; fr[4*q+2] = t.z; fr[4*q+3] = t.w;
        }
      }
      #pragma unroll
      for (int r = 0; r < 4; ++r){
        float w[36];
        const float4* wp = (const float4*)(sin_ + (oy + r + fy) * 96 + ox);
        #pragma unroll
        for (int q = 0; q < 9; ++q){
          float4 t = wp[q];
          w[4*q+0] = t.x; w[4*q+1] = t.y; w[4*q+2] = t.z; w[4*q+3] = t.w;
        }
        #pragma unroll
        for (int fx = 0; fx < 33; ++fx){
          #pragma unroll
          for (int c = 0; c < 4; ++c){
            acc[r][c] = fmaf(fr[fx], w[fx + c], acc[r][c]);
          }
        }
      }
    }
    const float pr = prior[d];
    #pragma unroll
    for (int r = 0; r < 4; ++r)
      #pragma unroll
      for (int c = 0; c < 4; ++c){
        float v = acc[r][c] * pr;
        int i = (r << 2) + c;
        if (v > bv[i]){ bv[i] = v; bd[i] = d; }   // ascending d: strict > keeps smallest d
      }
  }

  u64* pb = packed + b * NPIX;
  #pragma unroll
  for (int r = 0; r < 4; ++r)
    #pragma unroll
    for (int c = 0; c < 4; ++c){
      int x = tX + oy + r, y = tY + ox + c;
      int i = (r << 2) + c;
      u64 key = ((u64)fsort(bv[i]) << 32) | (u64)(63 - bd[i]); // tie -> smaller d
      atomicMax(&pb[(x << 8) + y], key);
    }
}

// ---------------- per-iteration: apply deadzone, scan for argmax + umax -----
__global__ __launch_bounds__(256) void scan_kernel(
    const u64* __restrict__ packed, float* __restrict__ u, const int* __restrict__ pxy,
    float* __restrict__ smax, int* __restrict__ sidx, float* __restrict__ umax)
{
  const int b   = blockIdx.y;
  const int blk = blockIdx.x;          // 0..31
  const int tid = threadIdx.x;
  const int px = pxy[2 * b], py = pxy[2 * b + 1];
  const int base = blk * 2048;

  float lmax = -3e38f; int lidx = 0; float lu = 0.f;
  for (int k = tid; k < 2048; k += 256){
    const int p = base + k;
    const int idx = b * NPIX + p;
    float uu = u[idx];
    int x = p >> 8, y = p & 255;
    float dx = (float)(x - px), dy = (float)(y - py);
    float d2 = dx * dx + dy * dy;
    float t = 1.f - __expf(d2 * -0.03125f);     // 1/(2*sigma^2), sigma=4
    if (d2 <= 16.f) t = 0.f;                    // hard cutout r=4
    uu *= t;
    u[idx] = uu;
    float bvv = funsort((u32)(packed[idx] >> 32));
    float s = bvv * uu;
    if (s > lmax || (s == lmax && p < lidx)){ lmax = s; lidx = p; }
    if (uu > lu) lu = uu;
  }
  __shared__ float rmax[256]; __shared__ int rid[256]; __shared__ float rum[256];
  rmax[tid] = lmax; rid[tid] = lidx; rum[tid] = lu;
  __syncthreads();
  for (int s = 128; s > 0; s >>= 1){
    if (tid < s){
      float v2 = rmax[tid + s]; int i2 = rid[tid + s];
      if (v2 > rmax[tid] || (v2 == rmax[tid] && i2 < rid[tid])){ rmax[tid] = v2; rid[tid] = i2; }
      if (rum[tid + s] > rum[tid]) rum[tid] = rum[tid + s];
    }
    __syncthreads();
  }
  if (tid == 0){
    smax[b * 32 + blk] = rmax[0];
    sidx[b * 32 + blk] = rid[0];
    umax[b * 32 + blk] = rum[0];
  }
}

// ---------------- finalize iteration: reduce 32 partials, emit outputs ------
__global__ void final_kernel(const u64* __restrict__ packed, const float* __restrict__ prior,
    const float* __restrict__ smax, const int* __restrict__ sidx, const float* __restrict__ umax,
    int* __restrict__ pxy, float* __restrict__ out, int t)
{
  const int b = blockIdx.x;
  const int lane = threadIdx.x;   // 64 threads, entries in lanes 0..31
  float v = -3e38f; int id = 0x7fffffff; float um = 0.f;
  if (lane < 32){ v = smax[b * 32 + lane]; id = sidx[b * 32 + lane]; um = umax[b * 32 + lane]; }
  #pragma unroll
  for (int off = 32; off > 0; off >>= 1){
    float v2 = __shfl_down(v, off);
    int   i2 = __shfl_down(id, off);
    float u2 = __shfl_down(um, off);
    if (v2 > v || (v2 == v && i2 < id)){ v = v2; id = i2; }
    if (u2 > um) um = u2;
  }
  if (lane == 0){
    int x = id >> 8, y = id & 255;
    u64 key = packed[b * NPIX + id];
    int d = 63 - (int)(key & 63ull);
    float bvv = funsort((u32)(key >> 32));
    out[b * 30 + t * 3 + 0] = (float)d;     // position_found [B,10,3]
    out[b * 30 + t * 3 + 1] = (float)x;
    out[b * 30 + t * 3 + 2] = (float)y;
    out[240 + b * 20 + t * 2 + 0] = v / um;        // ov0: max incl. prior (normalized u)
    out[240 + b * 20 + t * 2 + 1] = bvv / prior[d];// ov1: raw conv value
    pxy[2 * b] = x; pxy[2 * b + 1] = y;
  }
}

extern "C" void kernel_launch(void* const* d_in, const int* in_sizes, int n_in,
                              void* d_out, int out_size, void* d_ws, size_t ws_size,
                              hipStream_t stream)
{
  const float* input = (const float*)d_in[0];
  const float* filt  = (const float*)d_in[1];
  // d_in[2] (dictionary) is unused by the reference
  const float* prior = (const float*)d_in[3];
  float* out = (float*)d_out;

  char* ws = (char*)d_ws;
  u64*   packed = (u64*)(ws);                  // 8*65536*8 = 4,194,304 B
  float* u      = (float*)(ws + 4194304);      // 2,097,152 B
  float* smax   = (float*)(ws + 6291456);      // 1024 B
  int*   sidx   = (int*)  (ws + 6292480);      // 1024 B
  float* umax   = (float*)(ws + 6293504);      // 1024 B
  int*   pxy    = (int*)  (ws + 6294528);      // 64 B

  init_kernel<<<2048, 256, 0, stream>>>(packed, u, pxy);
  conv_best_kernel<<<dim3(16, NB, 4), 256, 0, stream>>>(input, filt, prior, packed);
  for (int t = 0; t < 10; ++t){
    scan_kernel<<<dim3(32, NB), 256, 0, stream>>>(packed, u, pxy, smax, sidx, umax);
    final_kernel<<<NB, 64, 0, stream>>>(packed, prior, smax, sidx, umax, pxy, out, t);
  }
}